// Round 1
// baseline (605.524 us; speedup 1.0000x reference)
//
#include <hip/hip_runtime.h>
#include <math.h>

typedef unsigned short u16;
typedef unsigned short u16x8 __attribute__((ext_vector_type(8)));
typedef __bf16 bf16x8 __attribute__((ext_vector_type(8)));
typedef float f32x4 __attribute__((ext_vector_type(4)));

#define B_ 8
#define C_ 2048
#define MID_ 512
#define N_ 2304

static __device__ __forceinline__ u16 f2bf(float f) {
  union { float f; unsigned u; } c; c.f = f;
  unsigned u = c.u;
  u += 0x7fffu + ((u >> 16) & 1u);   // round to nearest even
  return (u16)(u >> 16);
}

// ---------------- prep kernels ----------------
__global__ __launch_bounds__(256) void prep_wall_k(
    const float* __restrict__ fw, const float* __restrict__ gw,
    const float* __restrict__ hw, u16* __restrict__ wall) {
  int idx = blockIdx.x * 256 + threadIdx.x;
  if (idx >= 1536 * 2048) return;
  int r = idx >> 11;
  float v = (r < 512) ? fw[idx] : (r < 1024) ? gw[idx - (512 << 11)] : hw[idx - (1024 << 11)];
  wall[idx] = f2bf(v);
}

__global__ __launch_bounds__(256) void prep_vw_k(const float* __restrict__ vw, u16* __restrict__ o) {
  int idx = blockIdx.x * 256 + threadIdx.x;
  if (idx < 2048 * 512) o[idx] = f2bf(vw[idx]);
}

__global__ __launch_bounds__(256) void prep_sb_k(
    const float* fb, const float* fg, const float* fbe, const float* fm, const float* fv,
    const float* gb, const float* gg, const float* gbe, const float* gm, const float* gv,
    const float* hb, float* __restrict__ scale, float* __restrict__ bias) {
  int i = blockIdx.x * 256 + threadIdx.x;
  if (i >= 1536) return;
  if (i < 512) {
    float inv = fg[i] / sqrtf(fv[i] + 1e-5f);
    scale[i] = inv; bias[i] = fb[i] * inv + fbe[i] - fm[i] * inv;
  } else if (i < 1024) {
    int j = i - 512;
    float inv = gg[j] / sqrtf(gv[j] + 1e-5f);
    scale[i] = inv; bias[i] = gb[j] * inv + gbe[j] - gm[j] * inv;
  } else {
    scale[i] = 1.0f; bias[i] = hb[i - 1024];
  }
}

// x [B][C][N] f32 -> xT [B][N][C] bf16   (32x32 LDS tile transpose)
__global__ __launch_bounds__(256) void transpose_x_k(const float* __restrict__ x, u16* __restrict__ xT) {
  __shared__ float tile[32][33];
  int b = blockIdx.z;
  int n0 = blockIdx.x * 32, c0 = blockIdx.y * 32;
  int tx = threadIdx.x & 31, ty = threadIdx.x >> 5;
  const float* xb = x + (size_t)b * C_ * N_;
  u16* xTb = xT + (size_t)b * N_ * C_;
  #pragma unroll
  for (int i = 0; i < 4; ++i)
    tile[ty + i * 8][tx] = xb[(size_t)(c0 + ty + i * 8) * N_ + n0 + tx];
  __syncthreads();
  #pragma unroll
  for (int i = 0; i < 4; ++i)
    xTb[(size_t)(n0 + ty + i * 8) * C_ + c0 + tx] = f2bf(tile[tx][ty + i * 8]);
}

// ---------------- GEMM ----------------
// Computes OUT[M,N] = A[M,K] * B, where A is row-major contiguous-K.
// B_TRANS=true : Bg is B^T row-major [N][K] (contiguous-K)
// B_TRANS=false: Bg is B   row-major [K][N]
// A_F32: A operand is fp32 in global, converted to bf16 while staging.
#define EP_FGH 0      // v*scale[col]+bias[col], relu if col<1024, store bf16
#define EP_SCOREF32 1 // v*fscale, store f32
#define EP_BF16 2     // store bf16
#define EP_FINAL 3    // v + bias[row] + x[row*ldc+col], store f32

template<int EPI, bool A_F32, bool B_TRANS>
__global__ __launch_bounds__(256) void gemm_kernel(
    const void* __restrict__ Ag, int lda, long long strideA,
    const void* __restrict__ Bg, int ldb, long long strideB,
    void* __restrict__ Cg, int ldc, long long strideC,
    int K,
    const float* __restrict__ ep_scale, const float* __restrict__ ep_bias,
    const float* __restrict__ ep_x, long long strideX, float fscale)
{
  constexpr int BM = 128, BN = 128, BK = 32, LDST = BK + 8;
  __shared__ __align__(16) u16 Als[BM][LDST];
  __shared__ __align__(16) u16 Bls[BN][LDST];

  const int tid = threadIdx.x;
  const int b = blockIdx.z;
  const int m0 = blockIdx.y * BM;
  const int n0 = blockIdx.x * BN;

  const u16*   Ab = (const u16*)Ag + (size_t)b * strideA;
  const float* Af = (const float*)Ag + (size_t)b * strideA;
  const u16*   Bb = (const u16*)Bg + (size_t)b * strideB;

  f32x4 acc[4][4];
  #pragma unroll
  for (int i = 0; i < 4; ++i)
    #pragma unroll
    for (int j = 0; j < 4; ++j)
      acc[i][j] = f32x4{0.f, 0.f, 0.f, 0.f};

  const int lane = tid & 63;
  const int wv = tid >> 6;
  const int wm = (wv >> 1) * 64, wn = (wv & 1) * 64;
  const int lr = lane & 15, lg = lane >> 4;

  for (int kt = 0; kt < K; kt += BK) {
    __syncthreads();
    // stage A tile [BM][BK]
    #pragma unroll
    for (int it = 0; it < 2; ++it) {
      int idx = tid + it * 256;
      int row = idx >> 2, oct = idx & 3;
      if constexpr (A_F32) {
        const float* s = Af + (size_t)(m0 + row) * lda + kt + oct * 8;
        float4 v0 = *(const float4*)s;
        float4 v1 = *(const float4*)(s + 4);
        u16x8 w;
        w[0]=f2bf(v0.x); w[1]=f2bf(v0.y); w[2]=f2bf(v0.z); w[3]=f2bf(v0.w);
        w[4]=f2bf(v1.x); w[5]=f2bf(v1.y); w[6]=f2bf(v1.z); w[7]=f2bf(v1.w);
        *(u16x8*)&Als[row][oct * 8] = w;
      } else {
        *(u16x8*)&Als[row][oct * 8] =
            *(const u16x8*)(Ab + (size_t)(m0 + row) * lda + kt + oct * 8);
      }
    }
    // stage B tile -> Bls[col][k]
    if constexpr (B_TRANS) {
      #pragma unroll
      for (int it = 0; it < 2; ++it) {
        int idx = tid + it * 256;
        int row = idx >> 2, oct = idx & 3;
        *(u16x8*)&Bls[row][oct * 8] =
            *(const u16x8*)(Bb + (size_t)(n0 + row) * ldb + kt + oct * 8);
      }
    } else {
      #pragma unroll
      for (int it = 0; it < 2; ++it) {
        int idx = tid + it * 256;
        int col = idx & 127, ko = idx >> 7;   // 0..3
        u16x8 w;
        #pragma unroll
        for (int j = 0; j < 8; ++j)
          w[j] = Bb[(size_t)(kt + ko * 8 + j) * ldb + n0 + col];
        *(u16x8*)&Bls[col][ko * 8] = w;
      }
    }
    __syncthreads();
    // compute: each wave owns a 64x64 quadrant = 4x4 fragments of 16x16
    bf16x8 af[4], bfv[4];
    #pragma unroll
    for (int m = 0; m < 4; ++m) af[m] = *(const bf16x8*)&Als[wm + m * 16 + lr][lg * 8];
    #pragma unroll
    for (int n = 0; n < 4; ++n) bfv[n] = *(const bf16x8*)&Bls[wn + n * 16 + lr][lg * 8];
    #pragma unroll
    for (int m = 0; m < 4; ++m)
      #pragma unroll
      for (int n = 0; n < 4; ++n)
        acc[m][n] = __builtin_amdgcn_mfma_f32_16x16x32_bf16(af[m], bfv[n], acc[m][n], 0, 0, 0);
  }

  // epilogue: D row = 4*lg + r, col = lr within each 16x16 fragment (verified layout)
  u16*   C16 = (u16*)Cg + (size_t)b * strideC;
  float* C32 = (float*)Cg + (size_t)b * strideC;
  const float* xb = (EPI == EP_FINAL) ? (ep_x + (size_t)b * strideX) : nullptr;
  #pragma unroll
  for (int m = 0; m < 4; ++m) {
    #pragma unroll
    for (int n = 0; n < 4; ++n) {
      #pragma unroll
      for (int r = 0; r < 4; ++r) {
        int row = m0 + wm + m * 16 + lg * 4 + r;
        int col = n0 + wn + n * 16 + lr;
        float v = acc[m][n][r];
        if constexpr (EPI == EP_FGH) {
          v = v * ep_scale[col] + ep_bias[col];
          if (col < 1024) v = fmaxf(v, 0.f);
          C16[(size_t)row * ldc + col] = f2bf(v);
        } else if constexpr (EPI == EP_SCOREF32) {
          C32[(size_t)row * ldc + col] = v * fscale;
        } else if constexpr (EPI == EP_BF16) {
          C16[(size_t)row * ldc + col] = f2bf(v);
        } else {
          v += ep_bias[row] + xb[(size_t)row * ldc + col];
          C32[(size_t)row * ldc + col] = v;
        }
      }
    }
  }
}

// ---------------- softmax (rows of 2304, in place, fp32) ----------------
__global__ __launch_bounds__(256) void softmax_k(float* __restrict__ attn) {
  float* r = attn + (size_t)blockIdx.x * N_;
  const int tid = threadIdx.x;
  float v[9];
  float mx = -3.0e38f;
  #pragma unroll
  for (int j = 0; j < 9; ++j) { v[j] = r[tid + j * 256]; mx = fmaxf(mx, v[j]); }
  #pragma unroll
  for (int o = 32; o; o >>= 1) mx = fmaxf(mx, __shfl_xor(mx, o));
  __shared__ float red[4], red2[4];
  if ((tid & 63) == 0) red[tid >> 6] = mx;
  __syncthreads();
  mx = fmaxf(fmaxf(red[0], red[1]), fmaxf(red[2], red[3]));
  float s = 0.f;
  #pragma unroll
  for (int j = 0; j < 9; ++j) { v[j] = __expf(v[j] - mx); s += v[j]; }
  #pragma unroll
  for (int o = 32; o; o >>= 1) s += __shfl_xor(s, o);
  if ((tid & 63) == 0) red2[tid >> 6] = s;
  __syncthreads();
  s = red2[0] + red2[1] + red2[2] + red2[3];
  float inv = 1.0f / s;
  #pragma unroll
  for (int j = 0; j < 9; ++j) r[tid + j * 256] = v[j] * inv;
}

// ---------------- launch ----------------
extern "C" void kernel_launch(void* const* d_in, const int* in_sizes, int n_in,
                              void* d_out, int out_size, void* d_ws, size_t ws_size,
                              hipStream_t stream) {
  const float* x    = (const float*)d_in[0];
  const float* f_w  = (const float*)d_in[1];
  const float* f_b  = (const float*)d_in[2];
  const float* f_ga = (const float*)d_in[3];
  const float* f_be = (const float*)d_in[4];
  const float* f_me = (const float*)d_in[5];
  const float* f_va = (const float*)d_in[6];
  const float* g_w  = (const float*)d_in[7];
  const float* g_b  = (const float*)d_in[8];
  const float* g_ga = (const float*)d_in[9];
  const float* g_be = (const float*)d_in[10];
  const float* g_me = (const float*)d_in[11];
  const float* g_va = (const float*)d_in[12];
  const float* h_w  = (const float*)d_in[13];
  const float* h_b  = (const float*)d_in[14];
  const float* v_w  = (const float*)d_in[15];
  const float* v_b  = (const float*)d_in[16];

  float* out0 = (float*)d_out;
  float* attn = out0 + (size_t)B_ * C_ * N_;   // second output region

  // workspace carve (~152 MB total)
  char* p = (char*)d_ws;
  u16* xT   = (u16*)p; p += (size_t)B_ * N_ * C_ * 2;       // 75.5 MB
  u16* fghT = (u16*)p; p += (size_t)B_ * N_ * 1536 * 2;     // 56.6 MB
  u16* ZT   = (u16*)p; p += (size_t)B_ * N_ * MID_ * 2;     // 18.9 MB
  u16* Wall = (u16*)p; p += (size_t)1536 * C_ * 2;          // 6.3 MB
  u16* vwb  = (u16*)p; p += (size_t)C_ * MID_ * 2;          // 2.1 MB
  float* sc = (float*)p; p += 1536 * 4;
  float* bi = (float*)p; p += 1536 * 4;

  prep_wall_k<<<(1536 * 2048 + 255) / 256, 256, 0, stream>>>(f_w, g_w, h_w, Wall);
  prep_vw_k<<<(2048 * 512 + 255) / 256, 256, 0, stream>>>(v_w, vwb);
  prep_sb_k<<<6, 256, 0, stream>>>(f_b, f_ga, f_be, f_me, f_va,
                                   g_b, g_ga, g_be, g_me, g_va, h_b, sc, bi);
  transpose_x_k<<<dim3(N_ / 32, C_ / 32, B_), 256, 0, stream>>>(x, xT);

  // G1: fghT[n][c'] = sum_k xT[n][k] * Wall[c'][k]; BN+bias(+relu) epilogue -> bf16
  gemm_kernel<EP_FGH, false, true><<<dim3(1536 / 128, N_ / 128, B_), 256, 0, stream>>>(
      xT, C_, (long long)N_ * C_, Wall, C_, 0,
      fghT, 1536, (long long)N_ * 1536, C_, sc, bi, nullptr, 0, 0.f);

  // G2: scores[n][m] = sum_c fT[n][c] * gT[m][c] * mid^-0.5  -> f32 into attn region
  const float fscale = 0.044194173824159216f;  // 512^-0.5
  gemm_kernel<EP_SCOREF32, false, true><<<dim3(N_ / 128, N_ / 128, B_), 256, 0, stream>>>(
      fghT, 1536, (long long)N_ * 1536, fghT + 512, 1536, (long long)N_ * 1536,
      attn, N_, (long long)N_ * N_, MID_, nullptr, nullptr, nullptr, 0, fscale);

  softmax_k<<<B_ * N_, 256, 0, stream>>>(attn);

  // G3: ZT[n][c] = sum_m attn[n][m] * hT[m][c]   (A: f32 attn; B: OpB=N transpose-stage)
  gemm_kernel<EP_BF16, true, false><<<dim3(MID_ / 128, N_ / 128, B_), 256, 0, stream>>>(
      attn, N_, (long long)N_ * N_, fghT + 1024, 1536, (long long)N_ * 1536,
      ZT, MID_, (long long)N_ * MID_, N_, nullptr, nullptr, nullptr, 0, 0.f);

  // G5: out[o][n] = sum_c vw[o][c] * ZT[n][c] + v_b[o] + x[o][n] -> f32
  gemm_kernel<EP_FINAL, false, true><<<dim3(N_ / 128, C_ / 128, B_), 256, 0, stream>>>(
      vwb, MID_, 0, ZT, MID_, (long long)N_ * MID_,
      out0, N_, (long long)C_ * N_, MID_, nullptr, v_b, x, (long long)C_ * N_, 0.f);
}